// Round 1
// baseline (89.684 us; speedup 1.0000x reference)
//
#include <hip/hip_runtime.h>
#include <hip/hip_bf16.h>

// Euler characteristic curve (ECC) of V-construction cubical complex.
// x: [64,3,224,224] fp32 in [0,1). Out: [64, 96] fp32 = per-(b,c) ECC over
// tseq = linspace(0,1,32). Flattened out index = img*32 + t  (img = b*3+c).
//
// Per pixel (i,j): cells with top-left corner at (i,j):
//   vertex  f = x[i][j]                                  sign +1
//   h-edge  f = max(x[i][j], x[i][j+1])     (j<W-1)      sign -1
//   v-edge  f = max(x[i][j], x[i+1][j])     (i<H-1)      sign -1
//   square  f = max of 2x2                  (both)       sign +1
// bin idx = first t with tseq[t] >= f  ==  ceil(31*f) for f in [0,1).

#define H 224
#define W 224
#define STEPS 32
#define BANDS 8
#define ROWS_PER_BLOCK (H / BANDS)   // 28
#define NTHR 256

__device__ __forceinline__ int bin_of(float f) {
    int i = (int)ceilf(f * 31.0f);
    // f in [0,1) => i in [0,31]; clamp defensively
    return i > 31 ? 31 : (i < 0 ? 0 : i);
}

__global__ __launch_bounds__(NTHR) void ecc_hist_kernel(
        const float* __restrict__ x, int* __restrict__ ghist)
{
    // Per-thread privatized i16 histograms, bin-major: lh[bin*NTHR + tid].
    // Lane bank = (tid/2)%32 regardless of bin -> 2-way conflict (free).
    __shared__ short lh[STEPS * NTHR];      // 16 KB
    __shared__ int   partial[NTHR];         // 1 KB

    const int tid = threadIdx.x;
    for (int b = 0; b < STEPS; ++b) lh[b * NTHR + tid] = 0;
    __syncthreads();

    const int band = blockIdx.x & (BANDS - 1);
    const int img  = blockIdx.x / BANDS;          // 0..191
    const float* __restrict__ p = x + (size_t)img * (H * W);
    const int r0 = band * ROWS_PER_BLOCK;

    const int j = tid;
    if (j < W) {
        const bool hasR = (j < W - 1);
        float cur  = p[r0 * W + j];
        float curR = hasR ? p[r0 * W + j + 1] : 0.0f;
        #pragma unroll 4
        for (int r = r0; r < r0 + ROWS_PER_BLOCK; ++r) {
            const bool hasD = (r < H - 1);
            float dn  = hasD ? p[(r + 1) * W + j] : 0.0f;
            float dnR = (hasD && hasR) ? p[(r + 1) * W + j + 1] : 0.0f;

            // vertex (+1)
            lh[bin_of(cur) * NTHR + tid]++;
            if (hasR) {                      // h-edge (-1)
                lh[bin_of(fmaxf(cur, curR)) * NTHR + tid]--;
            }
            if (hasD) {                      // v-edge (-1)
                lh[bin_of(fmaxf(cur, dn)) * NTHR + tid]--;
                if (hasR) {                  // square (+1)
                    float m = fmaxf(fmaxf(cur, curR), fmaxf(dn, dnR));
                    lh[bin_of(m) * NTHR + tid]++;
                }
            }
            cur = dn; curR = dnR;
        }
    }
    __syncthreads();

    // Reduce 256 thread-hists -> 32 bins. thread = g*32 + b, g in [0,8).
    const int b = tid & 31;
    const int g = tid >> 5;
    int sum = 0;
    #pragma unroll
    for (int k = 0; k < 32; ++k) sum += (int)lh[b * NTHR + g * 32 + k];
    partial[g * 32 + b] = sum;
    __syncthreads();

    if (tid < 32) {
        int s = 0;
        #pragma unroll
        for (int gg = 0; gg < 8; ++gg) s += partial[gg * 32 + tid];
        atomicAdd(&ghist[img * STEPS + tid], s);
    }
}

__global__ void ecc_cumsum_kernel(const int* __restrict__ ghist,
                                  float* __restrict__ out, int nimg)
{
    int img = blockIdx.x * blockDim.x + threadIdx.x;
    if (img < nimg) {
        int s = 0;
        #pragma unroll
        for (int t = 0; t < STEPS; ++t) {
            s += ghist[img * STEPS + t];
            out[img * STEPS + t] = (float)s;
        }
    }
}

extern "C" void kernel_launch(void* const* d_in, const int* in_sizes, int n_in,
                              void* d_out, int out_size, void* d_ws, size_t ws_size,
                              hipStream_t stream) {
    const float* x = (const float*)d_in[0];
    float* out = (float*)d_out;
    int* ghist = (int*)d_ws;

    const int nimg = in_sizes[0] / (H * W);      // 192

    hipMemsetAsync(ghist, 0, (size_t)nimg * STEPS * sizeof(int), stream);

    dim3 grid1(nimg * BANDS);
    ecc_hist_kernel<<<grid1, NTHR, 0, stream>>>(x, ghist);

    int thr2 = 256;
    int blk2 = (nimg + thr2 - 1) / thr2;
    ecc_cumsum_kernel<<<blk2, thr2, 0, stream>>>(ghist, out, nimg);
}